// Round 5
// baseline (100.096 us; speedup 1.0000x reference)
//
#include <hip/hip_runtime.h>
#include <hip/hip_bf16.h>

// Problem constants (fixed by the reference's setup_inputs)
#define BB 2
#define CC 256      // channels per level
#define HH 100
#define WW 100
#define NN 256      // rois per batch
#define KK (BB*NN)  // 512 total rois
#define C3 (3*CC)   // 768 fused channels
#define OUTB 7
#define SR 2
#define NSAMP (OUTB*SR)   // 14 sample positions per axis
#define BINS (OUTB*OUTB)  // 49

__device__ __forceinline__ unsigned int f2bf(float f) {      // RNE f32->bf16 bits
    unsigned int b = __float_as_uint(f);
    return (b + 0x7FFFu + ((b >> 16) & 1u)) >> 16;
}
__device__ __forceinline__ float bf_lo(unsigned int u) { return __uint_as_float(u << 16); }
__device__ __forceinline__ float bf_hi(unsigned int u) { return __uint_as_float(u & 0xFFFF0000u); }

// ---------------------------------------------------------------------------
// build_F: fused (x0 | 2x-up x1 | 4x-up x2) feature, channel-last bf16
// F[b][pos][c].  LDS tile transpose; bf16 pack on the write side.
// Upsample matches jax.image.resize 'bilinear': src = (i+0.5)/s - 0.5, clamped.
// ---------------------------------------------------------------------------
__global__ __launch_bounds__(256) void build_F(const float* __restrict__ x0,
                                               const float* __restrict__ x1,
                                               const float* __restrict__ x2,
                                               unsigned int* __restrict__ F) {
    __shared__ float tile[64][65];           // [c_local][p_local], +1 pad
    const int ptile = blockIdx.x;            // 157 tiles of 64 positions
    const int ctile = blockIdx.y;            // 12 tiles of 64 channels
    const int b     = blockIdx.z;
    const int tid   = threadIdx.x;

    const int level = ctile >> 2;            // 0: x0, 1: x1(2x), 2: x2(4x)
    const int cbase = (ctile & 3) * 64;      // channel offset within level

    if (level == 0) {
        // float4 along pos: lane f (0..15) owns pos4 = f*4, c rows via loop.
        const int f  = tid & 15;
        const int cr = tid >> 4;             // 0..15
        const int p4 = ptile*64 + f*4;       // HH*WW % 4 == 0 -> all-or-nothing
        if (p4 + 3 < HH*WW) {
            const float* p = x0 + (size_t)b*CC*(HH*WW);
            #pragma unroll
            for (int r = 0; r < 4; ++r) {
                int c_local = r*16 + cr;
                float4 v = *(const float4*)(p + (size_t)(cbase + c_local)*(HH*WW) + p4);
                tile[c_local][f*4+0] = v.x;
                tile[c_local][f*4+1] = v.y;
                tile[c_local][f*4+2] = v.z;
                tile[c_local][f*4+3] = v.w;
            }
        }
    } else {
        const int lane = tid & 63;
        const int grp  = tid >> 6;           // 0..3
        const int pos  = ptile*64 + lane;
        if (pos < HH*WW) {
            const int   L = (level == 1) ? 50 : 25;
            const float s = (level == 1) ? 0.5f  : 0.25f;
            const float t = (level == 1) ? 0.25f : 0.375f;
            const float* src = (level == 1) ? x1 : x2;
            const int y = pos / WW, x = pos - (pos / WW) * WW;
            float cy = fminf(fmaxf((float)y * s - t, 0.0f), (float)(L - 1));
            float cx = fminf(fmaxf((float)x * s - t, 0.0f), (float)(L - 1));
            int yl = (int)cy, xl = (int)cx;
            int yh = min(yl + 1, L - 1), xh = min(xl + 1, L - 1);
            float fy = cy - (float)yl, fx = cx - (float)xl;
            float w00 = (1.0f-fy)*(1.0f-fx), w01 = (1.0f-fy)*fx;
            float w10 = fy*(1.0f-fx),        w11 = fy*fx;
            int o00 = yl*L+xl, o01 = yl*L+xh, o10 = yh*L+xl, o11 = yh*L+xh;
            const float* p = src + ((size_t)b*CC + cbase)*(size_t)(L*L);
            #pragma unroll
            for (int r = 0; r < 16; ++r) {
                int c_local = r*4 + grp;
                const float* q = p + (size_t)c_local*(L*L);
                tile[c_local][lane] = q[o00]*w00 + q[o01]*w01 + q[o10]*w10 + q[o11]*w11;
            }
        }
    }
    __syncthreads();

    // write: 16 lanes x 4 bf16 channels (uint2 = 8B), 4 pos rows per wave
    #pragma unroll
    for (int r = 0; r < 4; ++r) {
        int p_local = r*16 + (tid >> 4);
        int pp = ptile*64 + p_local;
        if (pp < HH*WW) {
            int c4 = (tid & 15) * 4;
            uint2 v;
            v.x = f2bf(tile[c4+0][p_local]) | (f2bf(tile[c4+1][p_local]) << 16);
            v.y = f2bf(tile[c4+2][p_local]) | (f2bf(tile[c4+3][p_local]) << 16);
            *(uint2*)(F + (((size_t)b*(HH*WW) + pp)*C3 + ctile*64 + c4) / 2) = v;
        }
    }
}

// ---------------------------------------------------------------------------
// roi5: block = (roi, 128-channel chunk), 256 threads = 32 slots x 8 bin-groups.
// Separable dedup: per (axis, bin) the 2 samples touch a contiguous run of
// <=4 rows/cols; merged weights (validity + 0.25 mean folded) precomputed in
// LDS. Gathers are uint2 (4 bf16 ch) -> ~6 loads/bin instead of 16.
// ---------------------------------------------------------------------------
__global__ __launch_bounds__(256, 6) void roi5(const uint2* __restrict__ F2,
                                               const float* __restrict__ boxes,
                                               const float* __restrict__ ratio_hw,
                                               const float* __restrict__ offset_tl,
                                               float* __restrict__ out) {
    __shared__ float tile[4 * 32 * 51];      // 26112 B, [j][slot][51] odd stride
    __shared__ int   s_start[2][OUTB];       // [axis][bin] first row/col
    __shared__ int   s_cnt[2][OUTB];         // run length 1..4
    __shared__ float s_w[2][OUTB][4];        // merged weights

    const int tid   = threadIdx.x;
    const int k     = blockIdx.x;            // roi 0..511
    const int chunk = blockIdx.y;            // channel chunk 0..5 (128 ch each)
    const int b     = k >> 8;                // N=256

    if (tid < 2*OUTB) {
        const int axis = tid / OUTB;         // 0 = y, 1 = x
        const int bin  = tid - axis*OUTB;
        float r0 = ratio_hw[0], o0 = offset_tl[0];
        float scale = (float)HH / (1250.0f * r0 + 2.0f * o0);
        const float* bx = boxes + (size_t)k * 4;
        float a, e;
        if (axis) { float rW = ratio_hw[2*b+1], left = offset_tl[2*b+1];
                    a = (bx[0]*rW + left)*scale; e = (bx[2]*rW + left)*scale; }
        else      { float rH = ratio_hw[2*b],   top  = offset_tl[2*b];
                    a = (bx[1]*rH + top)*scale;  e = (bx[3]*rH + top)*scale;  }
        float len = fmaxf(e - a, 1.0f);      // ALIGNED=False
        float bs = len * (1.0f / (float)OUTB);
        int lo[2], hi[2]; float fr[2], vv[2];
        #pragma unroll
        for (int s = 0; s < 2; ++s) {
            float g = (float)bin + 0.25f + 0.5f * (float)s;
            float p = a + g * bs;
            vv[s] = (p >= -1.0f && p <= (float)HH) ? 0.5f : 0.0f;  // 0.25 mean folded, 0.5/axis
            float cc = fminf(fmaxf(p, 0.0f), (float)(HH - 1));
            lo[s] = (int)floorf(cc);
            hi[s] = min(lo[s] + 1, HH - 1);
            fr[s] = cc - (float)lo[s];
        }
        const int st = lo[0];                // samples monotone -> contiguous run
        float w[4] = {0.f, 0.f, 0.f, 0.f};
        w[lo[0]-st] += vv[0]*(1.0f-fr[0]);  w[hi[0]-st] += vv[0]*fr[0];
        w[lo[1]-st] += vv[1]*(1.0f-fr[1]);  w[hi[1]-st] += vv[1]*fr[1];
        s_start[axis][bin] = st;
        s_cnt[axis][bin]   = hi[1] - st + 1;
        s_w[axis][bin][0] = w[0]; s_w[axis][bin][1] = w[1];
        s_w[axis][bin][2] = w[2]; s_w[axis][bin][3] = w[3];
    }
    __syncthreads();

    const int slot = tid & 31;               // 4-bf16-channel slot within chunk
    const int bg   = tid >> 5;               // bin group 0..7
    const uint2* Fb = F2 + (size_t)b*(HH*WW)*(C3/4) + chunk*32 + slot;

    for (int t = 0; t < 7; ++t) {
        const int bin = bg + 8*t;
        if (bin >= BINS) break;
        const int oy = bin / OUTB;
        const int ox = bin - oy*OUTB;
        const int ys = s_start[0][oy], ny = s_cnt[0][oy];
        const int xs = s_start[1][ox], nx = s_cnt[1][ox];
        float a0 = 0.f, a1 = 0.f, a2 = 0.f, a3 = 0.f;
        for (int jy = 0; jy < ny; ++jy) {
            const float wy = s_w[0][oy][jy];
            const uint2* row = Fb + (size_t)((ys + jy)*WW + xs) * (C3/4);
            for (int jx = 0; jx < nx; ++jx) {
                const float w = wy * s_w[1][ox][jx];
                uint2 u = row[(size_t)jx * (C3/4)];
                a0 += w * bf_lo(u.x);
                a1 += w * bf_hi(u.x);
                a2 += w * bf_lo(u.y);
                a3 += w * bf_hi(u.y);
            }
        }
        // channel c = slot*4 + j -> tile[j][slot][bin], row stride 51 (odd)
        tile[0*32*51 + slot*51 + bin] = a0;
        tile[1*32*51 + slot*51 + bin] = a1;
        tile[2*32*51 + slot*51 + bin] = a2;
        tile[3*32*51 + slot*51 + bin] = a3;
    }
    __syncthreads();

    // One contiguous, fully-coalesced 25 KB write per block.
    float* dst = out + ((size_t)k*C3 + (size_t)chunk*128) * BINS;
    for (int i = tid; i < 128*BINS; i += 256) {
        const int c = i / BINS;              // local channel 0..127
        const int bin = i - c*BINS;
        dst[i] = tile[(c & 3)*32*51 + (c >> 2)*51 + bin];
    }
}

// ---------------------------------------------------------------------------
// Fallback (no workspace): direct gather from sources, one float per thread.
// ---------------------------------------------------------------------------
__device__ __forceinline__ float feat_val(const float* __restrict__ x0,
                                          const float* __restrict__ x1,
                                          const float* __restrict__ x2,
                                          int b, int y, int x, int c) {
    if (c < CC) {
        return x0[(((size_t)b*CC + c)*HH + y)*WW + x];
    }
    const float* src;
    int L; float s, t; int cl;
    if (c < 2*CC) { src = x1; L = 50; s = 0.5f;  t = 0.25f;  cl = c - CC; }
    else          { src = x2; L = 25; s = 0.25f; t = 0.375f; cl = c - 2*CC; }
    float cy = fminf(fmaxf((float)y * s - t, 0.0f), (float)(L - 1));
    float cx = fminf(fmaxf((float)x * s - t, 0.0f), (float)(L - 1));
    int yl = (int)cy, xl = (int)cx;
    int yh = min(yl + 1, L - 1), xh = min(xl + 1, L - 1);
    float fy = cy - (float)yl, fx = cx - (float)xl;
    const float* p = src + (((size_t)b*CC + cl)*L)*L;
    float v00 = p[yl*L + xl], v01 = p[yl*L + xh];
    float v10 = p[yh*L + xl], v11 = p[yh*L + xh];
    float hy = 1.0f - fy, hx = 1.0f - fx;
    return v00*(hy*hx) + v01*(hy*fx) + v10*(fy*hx) + v11*(fy*fx);
}

__global__ __launch_bounds__(256) void roi_fallback(const float* __restrict__ x0,
                                                    const float* __restrict__ x1,
                                                    const float* __restrict__ x2,
                                                    const float* __restrict__ boxes,
                                                    const float* __restrict__ ratio_hw,
                                                    const float* __restrict__ offset_tl,
                                                    float* __restrict__ out) {
    __shared__ int   s_ylo[NSAMP], s_yhi[NSAMP], s_xlo[NSAMP], s_xhi[NSAMP];
    __shared__ float s_fy[NSAMP], s_fx[NSAMP];
    __shared__ int   s_vy[NSAMP], s_vx[NSAMP];

    const int tid = threadIdx.x;
    const int k = blockIdx.x;
    const int chunk = blockIdx.y;
    const int b = k >> 8;

    if (tid < 2*NSAMP) {
        float r0 = ratio_hw[0], o0 = offset_tl[0];
        float scale = (float)HH / (1250.0f * r0 + 2.0f * o0);
        float rH  = ratio_hw[2*b],  rW   = ratio_hw[2*b + 1];
        float top = offset_tl[2*b], left = offset_tl[2*b + 1];
        const float* bx = boxes + (size_t)k * 4;
        bool isx = (tid >= NSAMP);
        int i = isx ? tid - NSAMP : tid;
        float a, e;
        if (isx) { a = (bx[0]*rW + left)*scale; e = (bx[2]*rW + left)*scale; }
        else     { a = (bx[1]*rH + top)*scale;  e = (bx[3]*rH + top)*scale;  }
        float len = fmaxf(e - a, 1.0f);
        float bs = len * (1.0f / (float)OUTB);
        float g = (float)(i >> 1) + 0.25f + 0.5f * (float)(i & 1);
        float p = a + g * bs;
        int v = (p >= -1.0f && p <= (float)HH) ? 1 : 0;
        float cc = fminf(fmaxf(p, 0.0f), (float)(HH - 1));
        int lo = (int)floorf(cc);
        int hi = min(lo + 1, HH - 1);
        float fr = cc - (float)lo;
        if (isx) { s_xlo[i] = lo; s_xhi[i] = hi; s_fx[i] = fr; s_vx[i] = v; }
        else     { s_ylo[i] = lo; s_yhi[i] = hi; s_fy[i] = fr; s_vy[i] = v; }
    }
    __syncthreads();

    const int c = chunk * 256 + tid;
    for (int oy = 0; oy < OUTB; ++oy) {
        for (int ox = 0; ox < OUTB; ++ox) {
            float acc = 0.0f;
            #pragma unroll
            for (int sy = 0; sy < SR; ++sy) {
                const int iy = oy*SR + sy;
                #pragma unroll
                for (int sx = 0; sx < SR; ++sx) {
                    const int ix = ox*SR + sx;
                    if (s_vy[iy] && s_vx[ix]) {
                        const float fy = s_fy[iy], fx = s_fx[ix];
                        const float hy = 1.0f - fy, hx = 1.0f - fx;
                        float v00 = feat_val(x0,x1,x2,b, s_ylo[iy], s_xlo[ix], c);
                        float v01 = feat_val(x0,x1,x2,b, s_ylo[iy], s_xhi[ix], c);
                        float v10 = feat_val(x0,x1,x2,b, s_yhi[iy], s_xlo[ix], c);
                        float v11 = feat_val(x0,x1,x2,b, s_yhi[iy], s_xhi[ix], c);
                        acc += v00*(hy*hx) + v01*(hy*fx) + v10*(fy*hx) + v11*(fy*fx);
                    }
                }
            }
            out[(size_t)k*C3*BINS + (size_t)c*BINS + oy*OUTB + ox] = acc * 0.25f;
        }
    }
}

extern "C" void kernel_launch(void* const* d_in, const int* in_sizes, int n_in,
                              void* d_out, int out_size, void* d_ws, size_t ws_size,
                              hipStream_t stream) {
    const float* x0       = (const float*)d_in[0];
    const float* x1       = (const float*)d_in[1];
    const float* x2       = (const float*)d_in[2];
    const float* boxes    = (const float*)d_in[3];
    const float* ratio_hw = (const float*)d_in[4];
    const float* off_tl   = (const float*)d_in[5];
    float* out = (float*)d_out;

    const size_t needF = (size_t)BB * HH * WW * C3 * 2;  // 30.72 MB (bf16)
    if (ws_size >= needF) {
        unsigned int* F = (unsigned int*)d_ws;
        build_F<<<dim3((HH*WW + 63)/64, C3/64, BB), 256, 0, stream>>>(x0, x1, x2, F);
        roi5<<<dim3(KK, 6), 256, 0, stream>>>((const uint2*)F,
                                              boxes, ratio_hw, off_tl, out);
    } else {
        roi_fallback<<<dim3(KK, 3), 256, 0, stream>>>(x0, x1, x2,
                                                      boxes, ratio_hw, off_tl, out);
    }
}

// Round 6
// 79.397 us; speedup vs baseline: 1.2607x; 1.2607x over previous
//
#include <hip/hip_runtime.h>
#include <hip/hip_bf16.h>

// Problem constants (fixed by the reference's setup_inputs)
#define BB 2
#define CC 256      // channels per level
#define HH 100
#define WW 100
#define NN 256      // rois per batch
#define KK (BB*NN)  // 512 total rois
#define C3 (3*CC)   // 768 fused channels
#define OUTB 7
#define SR 2
#define NSAMP (OUTB*SR)   // 14 sample positions per axis
#define BINS (OUTB*OUTB)  // 49
#define CQ (C3/4)   // 192 uint2 (4 bf16 ch) per position

__device__ __forceinline__ unsigned int f2bf(float f) {      // RNE f32->bf16 bits
    unsigned int b = __float_as_uint(f);
    return (b + 0x7FFFu + ((b >> 16) & 1u)) >> 16;
}
__device__ __forceinline__ float bf_lo(unsigned int u) { return __uint_as_float(u << 16); }
__device__ __forceinline__ float bf_hi(unsigned int u) { return __uint_as_float(u & 0xFFFF0000u); }

// ---------------------------------------------------------------------------
// build_F: fused (x0 | 2x-up x1 | 4x-up x2) feature, channel-last bf16
// F[b][pos][c].  LDS tile transpose; bf16 pack on the write side.
// Upsample matches jax.image.resize 'bilinear': src = (i+0.5)/s - 0.5, clamped.
// ---------------------------------------------------------------------------
__global__ __launch_bounds__(256) void build_F(const float* __restrict__ x0,
                                               const float* __restrict__ x1,
                                               const float* __restrict__ x2,
                                               unsigned int* __restrict__ F) {
    __shared__ float tile[64][65];           // [c_local][p_local], +1 pad
    const int ptile = blockIdx.x;            // 157 tiles of 64 positions
    const int ctile = blockIdx.y;            // 12 tiles of 64 channels
    const int b     = blockIdx.z;
    const int tid   = threadIdx.x;

    const int level = ctile >> 2;            // 0: x0, 1: x1(2x), 2: x2(4x)
    const int cbase = (ctile & 3) * 64;      // channel offset within level

    if (level == 0) {
        // float4 along pos: lane f (0..15) owns pos4 = f*4, c rows via loop.
        const int f  = tid & 15;
        const int cr = tid >> 4;             // 0..15
        const int p4 = ptile*64 + f*4;       // HH*WW % 4 == 0 -> all-or-nothing
        if (p4 + 3 < HH*WW) {
            const float* p = x0 + (size_t)b*CC*(HH*WW);
            #pragma unroll
            for (int r = 0; r < 4; ++r) {
                int c_local = r*16 + cr;
                float4 v = *(const float4*)(p + (size_t)(cbase + c_local)*(HH*WW) + p4);
                tile[c_local][f*4+0] = v.x;
                tile[c_local][f*4+1] = v.y;
                tile[c_local][f*4+2] = v.z;
                tile[c_local][f*4+3] = v.w;
            }
        }
    } else {
        const int lane = tid & 63;
        const int grp  = tid >> 6;           // 0..3
        const int pos  = ptile*64 + lane;
        if (pos < HH*WW) {
            const int   L = (level == 1) ? 50 : 25;
            const float s = (level == 1) ? 0.5f  : 0.25f;
            const float t = (level == 1) ? 0.25f : 0.375f;
            const float* src = (level == 1) ? x1 : x2;
            const int y = pos / WW, x = pos - (pos / WW) * WW;
            float cy = fminf(fmaxf((float)y * s - t, 0.0f), (float)(L - 1));
            float cx = fminf(fmaxf((float)x * s - t, 0.0f), (float)(L - 1));
            int yl = (int)cy, xl = (int)cx;
            int yh = min(yl + 1, L - 1), xh = min(xl + 1, L - 1);
            float fy = cy - (float)yl, fx = cx - (float)xl;
            float w00 = (1.0f-fy)*(1.0f-fx), w01 = (1.0f-fy)*fx;
            float w10 = fy*(1.0f-fx),        w11 = fy*fx;
            int o00 = yl*L+xl, o01 = yl*L+xh, o10 = yh*L+xl, o11 = yh*L+xh;
            const float* p = src + ((size_t)b*CC + cbase)*(size_t)(L*L);
            #pragma unroll
            for (int r = 0; r < 16; ++r) {
                int c_local = r*4 + grp;
                const float* q = p + (size_t)c_local*(L*L);
                tile[c_local][lane] = q[o00]*w00 + q[o01]*w01 + q[o10]*w10 + q[o11]*w11;
            }
        }
    }
    __syncthreads();

    // write: 16 lanes x 4 bf16 channels (uint2 = 8B), 4 pos rows per wave
    #pragma unroll
    for (int r = 0; r < 4; ++r) {
        int p_local = r*16 + (tid >> 4);
        int pp = ptile*64 + p_local;
        if (pp < HH*WW) {
            int c4 = (tid & 15) * 4;
            uint2 v;
            v.x = f2bf(tile[c4+0][p_local]) | (f2bf(tile[c4+1][p_local]) << 16);
            v.y = f2bf(tile[c4+2][p_local]) | (f2bf(tile[c4+3][p_local]) << 16);
            *(uint2*)(F + (((size_t)b*(HH*WW) + pp)*C3 + ctile*64 + c4) / 2) = v;
        }
    }
}

// ---------------------------------------------------------------------------
// roi6: block = (roi, 128-channel chunk), 256 threads = 32 slots x 8 bin-groups.
// Separable merged weights as roi5, but the per-bin footprint is padded to a
// STATIC 4x4 (weights zero-filled, indices clamped) -> all 16 uint2 loads are
// issued back-to-back (MLP=16) instead of one latency-serialized load per
// runtime-loop iteration.  This attacks the vmcnt-serialization that kept
// roi4/roi5 pinned at ~66 us.
// ---------------------------------------------------------------------------
__global__ __launch_bounds__(256, 4) void roi6(const uint2* __restrict__ F2,
                                               const float* __restrict__ boxes,
                                               const float* __restrict__ ratio_hw,
                                               const float* __restrict__ offset_tl,
                                               float* __restrict__ out) {
    __shared__ float tile[4 * 32 * 51];      // 26112 B, [j][slot][51] odd stride
    __shared__ int   s_start[2][OUTB];       // [axis][bin] first row/col
    __shared__ float s_w[2][OUTB][4];        // merged weights (zero padded)

    const int tid   = threadIdx.x;
    const int k     = blockIdx.x;            // roi 0..511
    const int chunk = blockIdx.y;            // channel chunk 0..5 (128 ch each)
    const int b     = k >> 8;                // N=256

    if (tid < 2*OUTB) {
        const int axis = tid / OUTB;         // 0 = y, 1 = x
        const int bin  = tid - axis*OUTB;
        float r0 = ratio_hw[0], o0 = offset_tl[0];
        float scale = (float)HH / (1250.0f * r0 + 2.0f * o0);
        const float* bx = boxes + (size_t)k * 4;
        float a, e;
        if (axis) { float rW = ratio_hw[2*b+1], left = offset_tl[2*b+1];
                    a = (bx[0]*rW + left)*scale; e = (bx[2]*rW + left)*scale; }
        else      { float rH = ratio_hw[2*b],   top  = offset_tl[2*b];
                    a = (bx[1]*rH + top)*scale;  e = (bx[3]*rH + top)*scale;  }
        float len = fmaxf(e - a, 1.0f);      // ALIGNED=False
        float bs = len * (1.0f / (float)OUTB);
        int lo[2], hi[2]; float fr[2], vv[2];
        #pragma unroll
        for (int s = 0; s < 2; ++s) {
            float g = (float)bin + 0.25f + 0.5f * (float)s;
            float p = a + g * bs;
            vv[s] = (p >= -1.0f && p <= (float)HH) ? 0.5f : 0.0f;  // 0.25 mean folded, 0.5/axis
            float cc = fminf(fmaxf(p, 0.0f), (float)(HH - 1));
            lo[s] = (int)floorf(cc);
            hi[s] = min(lo[s] + 1, HH - 1);
            fr[s] = cc - (float)lo[s];
        }
        const int st = lo[0];                // samples monotone -> run fits in 4
        float w[4] = {0.f, 0.f, 0.f, 0.f};
        w[lo[0]-st] += vv[0]*(1.0f-fr[0]);  w[hi[0]-st] += vv[0]*fr[0];
        w[lo[1]-st] += vv[1]*(1.0f-fr[1]);  w[hi[1]-st] += vv[1]*fr[1];
        s_start[axis][bin] = st;
        s_w[axis][bin][0] = w[0]; s_w[axis][bin][1] = w[1];
        s_w[axis][bin][2] = w[2]; s_w[axis][bin][3] = w[3];
    }
    __syncthreads();

    const int slot = tid & 31;               // 4-bf16-channel slot within chunk
    const int bg   = tid >> 5;               // bin group 0..7
    const uint2* Fb = F2 + (size_t)b*(HH*WW)*CQ + chunk*32 + slot;

    #pragma unroll
    for (int t = 0; t < 7; ++t) {
        const int bin = bg + 8*t;
        if (bin < BINS) {
            const int oy = bin / OUTB;
            const int ox = bin - oy*OUTB;
            const int ys = s_start[0][oy];
            const int xs = s_start[1][ox];
            // clamped row pointers / col offsets (ys+1, xs+1 in-bounds by constr.)
            const uint2* r0p = Fb + (size_t)(ys*WW)*CQ;
            const uint2* r1p = r0p + WW*CQ;
            const uint2* r2p = Fb + (size_t)(min(ys+2, HH-1)*WW)*CQ;
            const uint2* r3p = Fb + (size_t)(min(ys+3, HH-1)*WW)*CQ;
            const int xo0 = xs*CQ;
            const int xo1 = xo0 + CQ;
            const int xo2 = min(xs+2, WW-1)*CQ;
            const int xo3 = min(xs+3, WW-1)*CQ;
            // 16 independent loads, all in flight before first use
            uint2 u00 = r0p[xo0], u01 = r0p[xo1], u02 = r0p[xo2], u03 = r0p[xo3];
            uint2 u10 = r1p[xo0], u11 = r1p[xo1], u12 = r1p[xo2], u13 = r1p[xo3];
            uint2 u20 = r2p[xo0], u21 = r2p[xo1], u22 = r2p[xo2], u23 = r2p[xo3];
            uint2 u30 = r3p[xo0], u31 = r3p[xo1], u32 = r3p[xo2], u33 = r3p[xo3];

            const float wy0 = s_w[0][oy][0], wy1 = s_w[0][oy][1];
            const float wy2 = s_w[0][oy][2], wy3 = s_w[0][oy][3];
            const float wx0 = s_w[1][ox][0], wx1 = s_w[1][ox][1];
            const float wx2 = s_w[1][ox][2], wx3 = s_w[1][ox][3];

            float a0 = 0.f, a1 = 0.f, a2 = 0.f, a3 = 0.f;
            #define ACC(U, WY, WX) { const float w_ = (WY)*(WX);            \
                a0 += w_ * bf_lo(U.x); a1 += w_ * bf_hi(U.x);               \
                a2 += w_ * bf_lo(U.y); a3 += w_ * bf_hi(U.y); }
            ACC(u00, wy0, wx0) ACC(u01, wy0, wx1) ACC(u02, wy0, wx2) ACC(u03, wy0, wx3)
            ACC(u10, wy1, wx0) ACC(u11, wy1, wx1) ACC(u12, wy1, wx2) ACC(u13, wy1, wx3)
            ACC(u20, wy2, wx0) ACC(u21, wy2, wx1) ACC(u22, wy2, wx2) ACC(u23, wy2, wx3)
            ACC(u30, wy3, wx0) ACC(u31, wy3, wx1) ACC(u32, wy3, wx2) ACC(u33, wy3, wx3)
            #undef ACC

            // channel c = slot*4 + j -> tile[j][slot][bin], row stride 51 (odd)
            tile[0*32*51 + slot*51 + bin] = a0;
            tile[1*32*51 + slot*51 + bin] = a1;
            tile[2*32*51 + slot*51 + bin] = a2;
            tile[3*32*51 + slot*51 + bin] = a3;
        }
    }
    __syncthreads();

    // One contiguous, fully-coalesced 25 KB write per block.
    float* dst = out + ((size_t)k*C3 + (size_t)chunk*128) * BINS;
    for (int i = tid; i < 128*BINS; i += 256) {
        const int c = i / BINS;              // local channel 0..127
        const int bin = i - c*BINS;
        dst[i] = tile[(c & 3)*32*51 + (c >> 2)*51 + bin];
    }
}

// ---------------------------------------------------------------------------
// Fallback (no workspace): direct gather from sources, one float per thread.
// ---------------------------------------------------------------------------
__device__ __forceinline__ float feat_val(const float* __restrict__ x0,
                                          const float* __restrict__ x1,
                                          const float* __restrict__ x2,
                                          int b, int y, int x, int c) {
    if (c < CC) {
        return x0[(((size_t)b*CC + c)*HH + y)*WW + x];
    }
    const float* src;
    int L; float s, t; int cl;
    if (c < 2*CC) { src = x1; L = 50; s = 0.5f;  t = 0.25f;  cl = c - CC; }
    else          { src = x2; L = 25; s = 0.25f; t = 0.375f; cl = c - 2*CC; }
    float cy = fminf(fmaxf((float)y * s - t, 0.0f), (float)(L - 1));
    float cx = fminf(fmaxf((float)x * s - t, 0.0f), (float)(L - 1));
    int yl = (int)cy, xl = (int)cx;
    int yh = min(yl + 1, L - 1), xh = min(xl + 1, L - 1);
    float fy = cy - (float)yl, fx = cx - (float)xl;
    const float* p = src + (((size_t)b*CC + cl)*L)*L;
    float v00 = p[yl*L + xl], v01 = p[yl*L + xh];
    float v10 = p[yh*L + xl], v11 = p[yh*L + xh];
    float hy = 1.0f - fy, hx = 1.0f - fx;
    return v00*(hy*hx) + v01*(hy*fx) + v10*(fy*hx) + v11*(fy*fx);
}

__global__ __launch_bounds__(256) void roi_fallback(const float* __restrict__ x0,
                                                    const float* __restrict__ x1,
                                                    const float* __restrict__ x2,
                                                    const float* __restrict__ boxes,
                                                    const float* __restrict__ ratio_hw,
                                                    const float* __restrict__ offset_tl,
                                                    float* __restrict__ out) {
    __shared__ int   s_ylo[NSAMP], s_yhi[NSAMP], s_xlo[NSAMP], s_xhi[NSAMP];
    __shared__ float s_fy[NSAMP], s_fx[NSAMP];
    __shared__ int   s_vy[NSAMP], s_vx[NSAMP];

    const int tid = threadIdx.x;
    const int k = blockIdx.x;
    const int chunk = blockIdx.y;
    const int b = k >> 8;

    if (tid < 2*NSAMP) {
        float r0 = ratio_hw[0], o0 = offset_tl[0];
        float scale = (float)HH / (1250.0f * r0 + 2.0f * o0);
        float rH  = ratio_hw[2*b],  rW   = ratio_hw[2*b + 1];
        float top = offset_tl[2*b], left = offset_tl[2*b + 1];
        const float* bx = boxes + (size_t)k * 4;
        bool isx = (tid >= NSAMP);
        int i = isx ? tid - NSAMP : tid;
        float a, e;
        if (isx) { a = (bx[0]*rW + left)*scale; e = (bx[2]*rW + left)*scale; }
        else     { a = (bx[1]*rH + top)*scale;  e = (bx[3]*rH + top)*scale;  }
        float len = fmaxf(e - a, 1.0f);
        float bs = len * (1.0f / (float)OUTB);
        float g = (float)(i >> 1) + 0.25f + 0.5f * (float)(i & 1);
        float p = a + g * bs;
        int v = (p >= -1.0f && p <= (float)HH) ? 1 : 0;
        float cc = fminf(fmaxf(p, 0.0f), (float)(HH - 1));
        int lo = (int)floorf(cc);
        int hi = min(lo + 1, HH - 1);
        float fr = cc - (float)lo;
        if (isx) { s_xlo[i] = lo; s_xhi[i] = hi; s_fx[i] = fr; s_vx[i] = v; }
        else     { s_ylo[i] = lo; s_yhi[i] = hi; s_fy[i] = fr; s_vy[i] = v; }
    }
    __syncthreads();

    const int c = chunk * 256 + tid;
    for (int oy = 0; oy < OUTB; ++oy) {
        for (int ox = 0; ox < OUTB; ++ox) {
            float acc = 0.0f;
            #pragma unroll
            for (int sy = 0; sy < SR; ++sy) {
                const int iy = oy*SR + sy;
                #pragma unroll
                for (int sx = 0; sx < SR; ++sx) {
                    const int ix = ox*SR + sx;
                    if (s_vy[iy] && s_vx[ix]) {
                        const float fy = s_fy[iy], fx = s_fx[ix];
                        const float hy = 1.0f - fy, hx = 1.0f - fx;
                        float v00 = feat_val(x0,x1,x2,b, s_ylo[iy], s_xlo[ix], c);
                        float v01 = feat_val(x0,x1,x2,b, s_ylo[iy], s_xhi[ix], c);
                        float v10 = feat_val(x0,x1,x2,b, s_yhi[iy], s_xlo[ix], c);
                        float v11 = feat_val(x0,x1,x2,b, s_yhi[iy], s_xhi[ix], c);
                        acc += v00*(hy*hx) + v01*(hy*fx) + v10*(fy*hx) + v11*(fy*fx);
                    }
                }
            }
            out[(size_t)k*C3*BINS + (size_t)c*BINS + oy*OUTB + ox] = acc * 0.25f;
        }
    }
}

extern "C" void kernel_launch(void* const* d_in, const int* in_sizes, int n_in,
                              void* d_out, int out_size, void* d_ws, size_t ws_size,
                              hipStream_t stream) {
    const float* x0       = (const float*)d_in[0];
    const float* x1       = (const float*)d_in[1];
    const float* x2       = (const float*)d_in[2];
    const float* boxes    = (const float*)d_in[3];
    const float* ratio_hw = (const float*)d_in[4];
    const float* off_tl   = (const float*)d_in[5];
    float* out = (float*)d_out;

    const size_t needF = (size_t)BB * HH * WW * C3 * 2;  // 30.72 MB (bf16)
    if (ws_size >= needF) {
        unsigned int* F = (unsigned int*)d_ws;
        build_F<<<dim3((HH*WW + 63)/64, C3/64, BB), 256, 0, stream>>>(x0, x1, x2, F);
        roi6<<<dim3(KK, 6), 256, 0, stream>>>((const uint2*)F,
                                              boxes, ratio_hw, off_tl, out);
    } else {
        roi_fallback<<<dim3(KK, 3), 256, 0, stream>>>(x0, x1, x2,
                                                      boxes, ratio_hw, off_tl, out);
    }
}

// Round 7
// 70.921 us; speedup vs baseline: 1.4114x; 1.1195x over previous
//
#include <hip/hip_runtime.h>
#include <hip/hip_bf16.h>

// Problem constants (fixed by the reference's setup_inputs)
#define BB 2
#define CC 256      // channels per level
#define HH 100
#define WW 100
#define NN 256      // rois per batch
#define KK (BB*NN)  // 512 total rois
#define C3 (3*CC)   // 768 fused channels
#define OUTB 7
#define SR 2
#define NSAMP (OUTB*SR)   // 14 sample positions per axis
#define BINS (OUTB*OUTB)  // 49
#define C8 (C3/8)   // 96 uint4 (8 bf16 ch) per position

__device__ __forceinline__ unsigned int f2bf(float f) {      // RNE f32->bf16 bits
    unsigned int b = __float_as_uint(f);
    return (b + 0x7FFFu + ((b >> 16) & 1u)) >> 16;
}
__device__ __forceinline__ float bf_lo(unsigned int u) { return __uint_as_float(u << 16); }
__device__ __forceinline__ float bf_hi(unsigned int u) { return __uint_as_float(u & 0xFFFF0000u); }

// ---------------------------------------------------------------------------
// build_F: fused (x0 | 2x-up x1 | 4x-up x2) feature, channel-last bf16
// F[b][pos][c].  LDS tile transpose; bf16 pack on the write side.
// Upsample matches jax.image.resize 'bilinear': src = (i+0.5)/s - 0.5, clamped.
// ---------------------------------------------------------------------------
__global__ __launch_bounds__(256) void build_F(const float* __restrict__ x0,
                                               const float* __restrict__ x1,
                                               const float* __restrict__ x2,
                                               unsigned int* __restrict__ F) {
    __shared__ float tile[64][68];           // row stride 272 B: 16B-aligned rows
    const int ptile = blockIdx.x;            // 157 tiles of 64 positions
    const int ctile = blockIdx.y;            // 12 tiles of 64 channels
    const int b     = blockIdx.z;
    const int tid   = threadIdx.x;

    const int level = ctile >> 2;            // 0: x0, 1: x1(2x), 2: x2(4x)
    const int cbase = (ctile & 3) * 64;      // channel offset within level

    if (level == 0) {
        // float4 along pos: lane f (0..15) owns pos4 = f*4; ds_write_b128.
        const int f  = tid & 15;
        const int cr = tid >> 4;             // 0..15
        const int p4 = ptile*64 + f*4;       // HH*WW % 4 == 0 -> all-or-nothing
        if (p4 + 3 < HH*WW) {
            const float* p = x0 + (size_t)b*CC*(HH*WW);
            #pragma unroll
            for (int r = 0; r < 4; ++r) {
                int c_local = r*16 + cr;
                float4 v = *(const float4*)(p + (size_t)(cbase + c_local)*(HH*WW) + p4);
                *(float4*)&tile[c_local][f*4] = v;
            }
        }
    } else {
        const int lane = tid & 63;
        const int grp  = tid >> 6;           // 0..3
        const int pos  = ptile*64 + lane;
        if (pos < HH*WW) {
            const int   L = (level == 1) ? 50 : 25;
            const float s = (level == 1) ? 0.5f  : 0.25f;
            const float t = (level == 1) ? 0.25f : 0.375f;
            const float* src = (level == 1) ? x1 : x2;
            const int y = pos / WW, x = pos - (pos / WW) * WW;
            float cy = fminf(fmaxf((float)y * s - t, 0.0f), (float)(L - 1));
            float cx = fminf(fmaxf((float)x * s - t, 0.0f), (float)(L - 1));
            int yl = (int)cy, xl = (int)cx;
            int yh = min(yl + 1, L - 1), xh = min(xl + 1, L - 1);
            float fy = cy - (float)yl, fx = cx - (float)xl;
            float w00 = (1.0f-fy)*(1.0f-fx), w01 = (1.0f-fy)*fx;
            float w10 = fy*(1.0f-fx),        w11 = fy*fx;
            int o00 = yl*L+xl, o01 = yl*L+xh, o10 = yh*L+xl, o11 = yh*L+xh;
            const float* p = src + ((size_t)b*CC + cbase)*(size_t)(L*L);
            #pragma unroll
            for (int r = 0; r < 16; ++r) {
                int c_local = r*4 + grp;
                const float* q = p + (size_t)c_local*(L*L);
                tile[c_local][lane] = q[o00]*w00 + q[o01]*w01 + q[o10]*w10 + q[o11]*w11;
            }
        }
    }
    __syncthreads();

    // write: 16 lanes x 4 bf16 channels (uint2 = 8B), 4 pos rows per wave
    #pragma unroll
    for (int r = 0; r < 4; ++r) {
        int p_local = r*16 + (tid >> 4);
        int pp = ptile*64 + p_local;
        if (pp < HH*WW) {
            int c4 = (tid & 15) * 4;
            uint2 v;
            v.x = f2bf(tile[c4+0][p_local]) | (f2bf(tile[c4+1][p_local]) << 16);
            v.y = f2bf(tile[c4+2][p_local]) | (f2bf(tile[c4+3][p_local]) << 16);
            *(uint2*)(F + (((size_t)b*(HH*WW) + pp)*C3 + ctile*64 + c4) / 2) = v;
        }
    }
}

// ---------------------------------------------------------------------------
// roi7: block = (roi, 128-channel chunk), 256 threads = 16 slots x 16 groups.
// Each slot owns 8 bf16 channels -> all gathers are dwordx4; static 4x4
// padded footprint keeps MLP=16 (round-6 win).  Per-channel load/addressing
// overhead halves vs roi6.
// ---------------------------------------------------------------------------
__global__ __launch_bounds__(256, 4) void roi7(const uint4* __restrict__ F4,
                                               const float* __restrict__ boxes,
                                               const float* __restrict__ ratio_hw,
                                               const float* __restrict__ offset_tl,
                                               float* __restrict__ out) {
    __shared__ float tile[8 * 16 * 51];      // 26112 B, [j][slot][51] odd stride
    __shared__ int   s_start[2][OUTB];       // [axis][bin] first row/col
    __shared__ float s_w[2][OUTB][4];        // merged weights (zero padded)

    const int tid   = threadIdx.x;
    const int k     = blockIdx.x;            // roi 0..511
    const int chunk = blockIdx.y;            // channel chunk 0..5 (128 ch each)
    const int b     = k >> 8;                // N=256

    if (tid < 2*OUTB) {
        const int axis = tid / OUTB;         // 0 = y, 1 = x
        const int bin  = tid - axis*OUTB;
        float r0 = ratio_hw[0], o0 = offset_tl[0];
        float scale = (float)HH / (1250.0f * r0 + 2.0f * o0);
        const float* bx = boxes + (size_t)k * 4;
        float a, e;
        if (axis) { float rW = ratio_hw[2*b+1], left = offset_tl[2*b+1];
                    a = (bx[0]*rW + left)*scale; e = (bx[2]*rW + left)*scale; }
        else      { float rH = ratio_hw[2*b],   top  = offset_tl[2*b];
                    a = (bx[1]*rH + top)*scale;  e = (bx[3]*rH + top)*scale;  }
        float len = fmaxf(e - a, 1.0f);      // ALIGNED=False
        float bs = len * (1.0f / (float)OUTB);
        int lo[2], hi[2]; float fr[2], vv[2];
        #pragma unroll
        for (int s = 0; s < 2; ++s) {
            float g = (float)bin + 0.25f + 0.5f * (float)s;
            float p = a + g * bs;
            vv[s] = (p >= -1.0f && p <= (float)HH) ? 0.5f : 0.0f;  // 0.25 mean folded
            float cc = fminf(fmaxf(p, 0.0f), (float)(HH - 1));
            lo[s] = (int)floorf(cc);
            hi[s] = min(lo[s] + 1, HH - 1);
            fr[s] = cc - (float)lo[s];
        }
        const int st = lo[0];                // samples monotone -> run fits in 4
        float w[4] = {0.f, 0.f, 0.f, 0.f};
        w[lo[0]-st] += vv[0]*(1.0f-fr[0]);  w[hi[0]-st] += vv[0]*fr[0];
        w[lo[1]-st] += vv[1]*(1.0f-fr[1]);  w[hi[1]-st] += vv[1]*fr[1];
        s_start[axis][bin] = st;
        s_w[axis][bin][0] = w[0]; s_w[axis][bin][1] = w[1];
        s_w[axis][bin][2] = w[2]; s_w[axis][bin][3] = w[3];
    }
    __syncthreads();

    const int slot = tid & 15;               // 8-bf16-channel slot within chunk
    const int bg   = tid >> 4;               // bin group 0..15
    const uint4* Fb = F4 + (size_t)b*(HH*WW)*C8 + chunk*16 + slot;

    #pragma unroll
    for (int t = 0; t < 4; ++t) {
        const int bin = bg + 16*t;
        if (bin < BINS) {
            const int oy = bin / OUTB;
            const int ox = bin - oy*OUTB;
            const int ys = s_start[0][oy];
            const int xs = s_start[1][ox];
            // clamped row pointers / col offsets (ys+1, xs+1 in-bounds by constr.)
            const uint4* r0p = Fb + (size_t)(ys*WW)*C8;
            const uint4* r1p = r0p + WW*C8;
            const uint4* r2p = Fb + (size_t)(min(ys+2, HH-1)*WW)*C8;
            const uint4* r3p = Fb + (size_t)(min(ys+3, HH-1)*WW)*C8;
            const int xo0 = xs*C8;
            const int xo1 = xo0 + C8;
            const int xo2 = min(xs+2, WW-1)*C8;
            const int xo3 = min(xs+3, WW-1)*C8;
            // 16 independent dwordx4 loads, all in flight before first use
            uint4 u00 = r0p[xo0], u01 = r0p[xo1], u02 = r0p[xo2], u03 = r0p[xo3];
            uint4 u10 = r1p[xo0], u11 = r1p[xo1], u12 = r1p[xo2], u13 = r1p[xo3];
            uint4 u20 = r2p[xo0], u21 = r2p[xo1], u22 = r2p[xo2], u23 = r2p[xo3];
            uint4 u30 = r3p[xo0], u31 = r3p[xo1], u32 = r3p[xo2], u33 = r3p[xo3];

            const float wy0 = s_w[0][oy][0], wy1 = s_w[0][oy][1];
            const float wy2 = s_w[0][oy][2], wy3 = s_w[0][oy][3];
            const float wx0 = s_w[1][ox][0], wx1 = s_w[1][ox][1];
            const float wx2 = s_w[1][ox][2], wx3 = s_w[1][ox][3];

            float a0=0.f,a1=0.f,a2=0.f,a3=0.f,a4=0.f,a5=0.f,a6=0.f,a7=0.f;
            #define ACC8(U, WY, WX) { const float w_ = (WY)*(WX);           \
                a0 += w_ * bf_lo(U.x); a1 += w_ * bf_hi(U.x);               \
                a2 += w_ * bf_lo(U.y); a3 += w_ * bf_hi(U.y);               \
                a4 += w_ * bf_lo(U.z); a5 += w_ * bf_hi(U.z);               \
                a6 += w_ * bf_lo(U.w); a7 += w_ * bf_hi(U.w); }
            ACC8(u00, wy0, wx0) ACC8(u01, wy0, wx1) ACC8(u02, wy0, wx2) ACC8(u03, wy0, wx3)
            ACC8(u10, wy1, wx0) ACC8(u11, wy1, wx1) ACC8(u12, wy1, wx2) ACC8(u13, wy1, wx3)
            ACC8(u20, wy2, wx0) ACC8(u21, wy2, wx1) ACC8(u22, wy2, wx2) ACC8(u23, wy2, wx3)
            ACC8(u30, wy3, wx0) ACC8(u31, wy3, wx1) ACC8(u32, wy3, wx2) ACC8(u33, wy3, wx3)
            #undef ACC8

            // channel c = slot*8 + j -> tile[j][slot][bin], row stride 51 (odd)
            tile[0*16*51 + slot*51 + bin] = a0;
            tile[1*16*51 + slot*51 + bin] = a1;
            tile[2*16*51 + slot*51 + bin] = a2;
            tile[3*16*51 + slot*51 + bin] = a3;
            tile[4*16*51 + slot*51 + bin] = a4;
            tile[5*16*51 + slot*51 + bin] = a5;
            tile[6*16*51 + slot*51 + bin] = a6;
            tile[7*16*51 + slot*51 + bin] = a7;
        }
    }
    __syncthreads();

    // One contiguous, fully-coalesced 25 KB write per block.
    float* dst = out + ((size_t)k*C3 + (size_t)chunk*128) * BINS;
    for (int i = tid; i < 128*BINS; i += 256) {
        const int c = i / BINS;              // local channel 0..127
        const int bin = i - c*BINS;
        dst[i] = tile[(c & 7)*16*51 + (c >> 3)*51 + bin];
    }
}

// ---------------------------------------------------------------------------
// Fallback (no workspace): direct gather from sources, one float per thread.
// ---------------------------------------------------------------------------
__device__ __forceinline__ float feat_val(const float* __restrict__ x0,
                                          const float* __restrict__ x1,
                                          const float* __restrict__ x2,
                                          int b, int y, int x, int c) {
    if (c < CC) {
        return x0[(((size_t)b*CC + c)*HH + y)*WW + x];
    }
    const float* src;
    int L; float s, t; int cl;
    if (c < 2*CC) { src = x1; L = 50; s = 0.5f;  t = 0.25f;  cl = c - CC; }
    else          { src = x2; L = 25; s = 0.25f; t = 0.375f; cl = c - 2*CC; }
    float cy = fminf(fmaxf((float)y * s - t, 0.0f), (float)(L - 1));
    float cx = fminf(fmaxf((float)x * s - t, 0.0f), (float)(L - 1));
    int yl = (int)cy, xl = (int)cx;
    int yh = min(yl + 1, L - 1), xh = min(xl + 1, L - 1);
    float fy = cy - (float)yl, fx = cx - (float)xl;
    const float* p = src + (((size_t)b*CC + cl)*L)*L;
    float v00 = p[yl*L + xl], v01 = p[yl*L + xh];
    float v10 = p[yh*L + xl], v11 = p[yh*L + xh];
    float hy = 1.0f - fy, hx = 1.0f - fx;
    return v00*(hy*hx) + v01*(hy*fx) + v10*(fy*hx) + v11*(fy*fx);
}

__global__ __launch_bounds__(256) void roi_fallback(const float* __restrict__ x0,
                                                    const float* __restrict__ x1,
                                                    const float* __restrict__ x2,
                                                    const float* __restrict__ boxes,
                                                    const float* __restrict__ ratio_hw,
                                                    const float* __restrict__ offset_tl,
                                                    float* __restrict__ out) {
    __shared__ int   s_ylo[NSAMP], s_yhi[NSAMP], s_xlo[NSAMP], s_xhi[NSAMP];
    __shared__ float s_fy[NSAMP], s_fx[NSAMP];
    __shared__ int   s_vy[NSAMP], s_vx[NSAMP];

    const int tid = threadIdx.x;
    const int k = blockIdx.x;
    const int chunk = blockIdx.y;
    const int b = k >> 8;

    if (tid < 2*NSAMP) {
        float r0 = ratio_hw[0], o0 = offset_tl[0];
        float scale = (float)HH / (1250.0f * r0 + 2.0f * o0);
        float rH  = ratio_hw[2*b],  rW   = ratio_hw[2*b + 1];
        float top = offset_tl[2*b], left = offset_tl[2*b + 1];
        const float* bx = boxes + (size_t)k * 4;
        bool isx = (tid >= NSAMP);
        int i = isx ? tid - NSAMP : tid;
        float a, e;
        if (isx) { a = (bx[0]*rW + left)*scale; e = (bx[2]*rW + left)*scale; }
        else     { a = (bx[1]*rH + top)*scale;  e = (bx[3]*rH + top)*scale;  }
        float len = fmaxf(e - a, 1.0f);
        float bs = len * (1.0f / (float)OUTB);
        float g = (float)(i >> 1) + 0.25f + 0.5f * (float)(i & 1);
        float p = a + g * bs;
        int v = (p >= -1.0f && p <= (float)HH) ? 1 : 0;
        float cc = fminf(fmaxf(p, 0.0f), (float)(HH - 1));
        int lo = (int)floorf(cc);
        int hi = min(lo + 1, HH - 1);
        float fr = cc - (float)lo;
        if (isx) { s_xlo[i] = lo; s_xhi[i] = hi; s_fx[i] = fr; s_vx[i] = v; }
        else     { s_ylo[i] = lo; s_yhi[i] = hi; s_fy[i] = fr; s_vy[i] = v; }
    }
    __syncthreads();

    const int c = chunk * 256 + tid;
    for (int oy = 0; oy < OUTB; ++oy) {
        for (int ox = 0; ox < OUTB; ++ox) {
            float acc = 0.0f;
            #pragma unroll
            for (int sy = 0; sy < SR; ++sy) {
                const int iy = oy*SR + sy;
                #pragma unroll
                for (int sx = 0; sx < SR; ++sx) {
                    const int ix = ox*SR + sx;
                    if (s_vy[iy] && s_vx[ix]) {
                        const float fy = s_fy[iy], fx = s_fx[ix];
                        const float hy = 1.0f - fy, hx = 1.0f - fx;
                        float v00 = feat_val(x0,x1,x2,b, s_ylo[iy], s_xlo[ix], c);
                        float v01 = feat_val(x0,x1,x2,b, s_ylo[iy], s_xhi[ix], c);
                        float v10 = feat_val(x0,x1,x2,b, s_yhi[iy], s_xlo[ix], c);
                        float v11 = feat_val(x0,x1,x2,b, s_yhi[iy], s_xhi[ix], c);
                        acc += v00*(hy*hx) + v01*(hy*fx) + v10*(fy*hx) + v11*(fy*fx);
                    }
                }
            }
            out[(size_t)k*C3*BINS + (size_t)c*BINS + oy*OUTB + ox] = acc * 0.25f;
        }
    }
}

extern "C" void kernel_launch(void* const* d_in, const int* in_sizes, int n_in,
                              void* d_out, int out_size, void* d_ws, size_t ws_size,
                              hipStream_t stream) {
    const float* x0       = (const float*)d_in[0];
    const float* x1       = (const float*)d_in[1];
    const float* x2       = (const float*)d_in[2];
    const float* boxes    = (const float*)d_in[3];
    const float* ratio_hw = (const float*)d_in[4];
    const float* off_tl   = (const float*)d_in[5];
    float* out = (float*)d_out;

    const size_t needF = (size_t)BB * HH * WW * C3 * 2;  // 30.72 MB (bf16)
    if (ws_size >= needF) {
        unsigned int* F = (unsigned int*)d_ws;
        build_F<<<dim3((HH*WW + 63)/64, C3/64, BB), 256, 0, stream>>>(x0, x1, x2, F);
        roi7<<<dim3(KK, 6), 256, 0, stream>>>((const uint4*)F,
                                              boxes, ratio_hw, off_tl, out);
    } else {
        roi_fallback<<<dim3(KK, 3), 256, 0, stream>>>(x0, x1, x2,
                                                      boxes, ratio_hw, off_tl, out);
    }
}

// Round 8
// 47.286 us; speedup vs baseline: 2.1168x; 1.4998x over previous
//
#include <hip/hip_runtime.h>
#include <hip/hip_bf16.h>

// Problem constants (fixed by the reference's setup_inputs)
#define BB 2
#define CC 256      // channels per level
#define HH 100      // roi-align grid (upsampled batch) H == W
#define NN 256      // rois per batch
#define KK (BB*NN)  // 512 total rois
#define C3 (3*CC)   // 768 fused channels
#define OUTB 7
#define SR 2
#define NSAMP (OUTB*SR)
#define BINS (OUTB*OUTB)  // 49
#define NP0 10000   // positions per level
#define NP1 2500
#define NP2 625
#define CQL 32      // uint4 (8 bf16 ch) per position in a 256-ch level buffer

__device__ __forceinline__ unsigned int f2bf(float f) {      // RNE f32->bf16 bits
    unsigned int b = __float_as_uint(f);
    return (b + 0x7FFFu + ((b >> 16) & 1u)) >> 16;
}
__device__ __forceinline__ float bf_lo(unsigned int u) { return __uint_as_float(u << 16); }
__device__ __forceinline__ float bf_hi(unsigned int u) { return __uint_as_float(u & 0xFFFF0000u); }

// ---------------------------------------------------------------------------
// transpose_all: NCHW -> NHWC bf16 for all three levels (no upsample!).
// The 2x/4x bilinear upsample is folded into roi8's composed weights.
// One block = 64ch x 64pos tile; coalesced float4 reads, uint2 bf16 writes.
// ---------------------------------------------------------------------------
__global__ __launch_bounds__(256) void transpose_all(const float* __restrict__ x0,
                                                     const float* __restrict__ x1,
                                                     const float* __restrict__ x2,
                                                     unsigned int* __restrict__ F0,
                                                     unsigned int* __restrict__ F1,
                                                     unsigned int* __restrict__ F2) {
    __shared__ float tile[64][68];           // 16B-aligned rows
    const int bx  = blockIdx.x;              // 0..206: 157 lvl0 | 40 lvl1 | 10 lvl2
    const int cbase = blockIdx.y * 64;       // channel tile
    const int b   = blockIdx.z;
    const int tid = threadIdx.x;

    const float* src; unsigned int* dst; int npos, ptile;
    if (bx < 157)      { src = x0; dst = F0; npos = NP0; ptile = bx; }
    else if (bx < 197) { src = x1; dst = F1; npos = NP1; ptile = bx - 157; }
    else               { src = x2; dst = F2; npos = NP2; ptile = bx - 197; }

    const int f  = tid & 15;                 // pos quad
    const int cr = tid >> 4;                 // channel row
    const int p4 = ptile*64 + f*4;
    const float* p = src + (size_t)b*CC*npos;
    #pragma unroll
    for (int r = 0; r < 4; ++r) {
        int c_local = r*16 + cr;
        const float* q = p + (size_t)(cbase + c_local)*npos;
        if (p4 + 3 < npos) {
            *(float4*)&tile[c_local][f*4] = *(const float4*)(q + p4);
        } else {
            #pragma unroll
            for (int j = 0; j < 4; ++j)
                tile[c_local][f*4+j] = (p4 + j < npos) ? q[p4+j] : 0.0f;
        }
    }
    __syncthreads();

    #pragma unroll
    for (int r = 0; r < 4; ++r) {
        int p_local = r*16 + (tid >> 4);
        int pp = ptile*64 + p_local;
        if (pp < npos) {
            int c4 = (tid & 15) * 4;
            uint2 v;
            v.x = f2bf(tile[c4+0][p_local]) | (f2bf(tile[c4+1][p_local]) << 16);
            v.y = f2bf(tile[c4+2][p_local]) | (f2bf(tile[c4+3][p_local]) << 16);
            *(uint2*)(dst + (((size_t)b*npos + pp)*CC + cbase + c4) / 2) = v;
        }
    }
}

// ---------------------------------------------------------------------------
// roi8: block = (roi, chunk 0..5); chunk -> (level = chunk>>1, half = chunk&1).
// Composed weights: roi bilinear (on the 100-grid) o bilinear upsample
// (100-grid -> level source grid, si = i*s - t, edge-clamped) collapses to a
// contiguous run <= 4 per axis on the SOURCE grid for every level.  Static
// 4x4 padded footprint keeps MLP=16 (round-6 win); per-channel width 8
// (round-7 win); levels 1/2 gather from L1/L2-hot 1.3/0.3 MB buffers.
// ---------------------------------------------------------------------------
__global__ __launch_bounds__(256, 4) void roi8(const uint4* __restrict__ F0,
                                               const uint4* __restrict__ F1,
                                               const uint4* __restrict__ F2,
                                               const float* __restrict__ boxes,
                                               const float* __restrict__ ratio_hw,
                                               const float* __restrict__ offset_tl,
                                               float* __restrict__ out) {
    __shared__ float tile[8 * 16 * 51];      // 26112 B, [j][slot][51] odd stride
    __shared__ int   s_start[2][OUTB];       // [axis][bin] first src row/col
    __shared__ float s_w[2][OUTB][4];        // composed merged weights

    const int tid   = threadIdx.x;
    const int k     = blockIdx.x;            // roi 0..511
    const int chunk = blockIdx.y;            // 0..5
    const int level = chunk >> 1;
    const int half  = chunk & 1;             // 128-ch half of the level
    const int b     = k >> 8;                // N=256

    const int   Ll = (level == 0) ? 100 : (level == 1 ? 50 : 25);
    const float sl = (level == 0) ? 1.0f : (level == 1 ? 0.5f  : 0.25f);
    const float tl = (level == 0) ? 0.0f : (level == 1 ? 0.25f : 0.375f);
    const uint4* Fl = (level == 0) ? F0 : (level == 1 ? F1 : F2);
    const int   np = (level == 0) ? NP0 : (level == 1 ? NP1 : NP2);

    if (tid < 2*OUTB) {
        const int axis = tid / OUTB;         // 0 = y, 1 = x
        const int bin  = tid - axis*OUTB;
        float r0 = ratio_hw[0], o0 = offset_tl[0];
        float scale = (float)HH / (1250.0f * r0 + 2.0f * o0);
        const float* bx = boxes + (size_t)k * 4;
        float a, e;
        if (axis) { float rW = ratio_hw[2*b+1], left = offset_tl[2*b+1];
                    a = (bx[0]*rW + left)*scale; e = (bx[2]*rW + left)*scale; }
        else      { float rH = ratio_hw[2*b],   top  = offset_tl[2*b];
                    a = (bx[1]*rH + top)*scale;  e = (bx[3]*rH + top)*scale;  }
        float len = fmaxf(e - a, 1.0f);      // ALIGNED=False
        float bs = len * (1.0f / (float)OUTB);
        float w[6] = {0.f,0.f,0.f,0.f,0.f,0.f};
        int st = -1;
        #pragma unroll
        for (int s = 0; s < 2; ++s) {
            float g = (float)bin + 0.25f + 0.5f*(float)s;
            float p = a + g*bs;
            float vv = (p >= -1.0f && p <= (float)HH) ? 0.5f : 0.0f;  // 0.25 mean folded
            float cc = fminf(fmaxf(p, 0.0f), (float)(HH - 1));
            int   i0 = (int)floorf(cc);      // up-grid neighbors
            float fu = cc - (float)i0;
            int   i1 = min(i0 + 1, HH - 1);
            #pragma unroll
            for (int j = 0; j < 2; ++j) {
                int   i  = j ? i1 : i0;
                float wu = j ? vv*fu : vv*(1.0f - fu);
                float si = fminf(fmaxf((float)i*sl - tl, 0.0f), (float)(Ll - 1));
                int   a0 = (int)floorf(si);  // source-grid neighbors
                float g2 = si - (float)a0;
                int   a1 = min(a0 + 1, Ll - 1);
                if (st < 0) st = a0;         // first contribution is minimal (monotone)
                w[a0 - st] += wu*(1.0f - g2);
                w[a1 - st] += wu*g2;         // index <= 4 only with weight exactly 0
            }
        }
        s_start[axis][bin] = st;
        s_w[axis][bin][0] = w[0]; s_w[axis][bin][1] = w[1];
        s_w[axis][bin][2] = w[2]; s_w[axis][bin][3] = w[3];
    }
    __syncthreads();

    const int slot = tid & 15;               // 8-bf16-channel slot within half
    const int bg   = tid >> 4;               // bin group 0..15
    const uint4* Fb = Fl + (size_t)b*np*CQL + half*16 + slot;

    #pragma unroll
    for (int t = 0; t < 4; ++t) {
        const int bin = bg + 16*t;
        if (bin < BINS) {
            const int oy = bin / OUTB;
            const int ox = bin - oy*OUTB;
            const int ys = s_start[0][oy];
            const int xs = s_start[1][ox];
            const int y1 = min(ys+1, Ll-1), y2 = min(ys+2, Ll-1), y3 = min(ys+3, Ll-1);
            const uint4* r0p = Fb + (size_t)(ys*Ll)*CQL;
            const uint4* r1p = Fb + (size_t)(y1*Ll)*CQL;
            const uint4* r2p = Fb + (size_t)(y2*Ll)*CQL;
            const uint4* r3p = Fb + (size_t)(y3*Ll)*CQL;
            const int xo0 = xs*CQL;
            const int xo1 = min(xs+1, Ll-1)*CQL;
            const int xo2 = min(xs+2, Ll-1)*CQL;
            const int xo3 = min(xs+3, Ll-1)*CQL;
            // 16 independent dwordx4 loads, all in flight before first use
            uint4 u00 = r0p[xo0], u01 = r0p[xo1], u02 = r0p[xo2], u03 = r0p[xo3];
            uint4 u10 = r1p[xo0], u11 = r1p[xo1], u12 = r1p[xo2], u13 = r1p[xo3];
            uint4 u20 = r2p[xo0], u21 = r2p[xo1], u22 = r2p[xo2], u23 = r2p[xo3];
            uint4 u30 = r3p[xo0], u31 = r3p[xo1], u32 = r3p[xo2], u33 = r3p[xo3];

            const float wy0 = s_w[0][oy][0], wy1 = s_w[0][oy][1];
            const float wy2 = s_w[0][oy][2], wy3 = s_w[0][oy][3];
            const float wx0 = s_w[1][ox][0], wx1 = s_w[1][ox][1];
            const float wx2 = s_w[1][ox][2], wx3 = s_w[1][ox][3];

            float a0=0.f,a1=0.f,a2=0.f,a3=0.f,a4=0.f,a5=0.f,a6=0.f,a7=0.f;
            #define ACC8(U, WY, WX) { const float w_ = (WY)*(WX);           \
                a0 += w_ * bf_lo(U.x); a1 += w_ * bf_hi(U.x);               \
                a2 += w_ * bf_lo(U.y); a3 += w_ * bf_hi(U.y);               \
                a4 += w_ * bf_lo(U.z); a5 += w_ * bf_hi(U.z);               \
                a6 += w_ * bf_lo(U.w); a7 += w_ * bf_hi(U.w); }
            ACC8(u00, wy0, wx0) ACC8(u01, wy0, wx1) ACC8(u02, wy0, wx2) ACC8(u03, wy0, wx3)
            ACC8(u10, wy1, wx0) ACC8(u11, wy1, wx1) ACC8(u12, wy1, wx2) ACC8(u13, wy1, wx3)
            ACC8(u20, wy2, wx0) ACC8(u21, wy2, wx1) ACC8(u22, wy2, wx2) ACC8(u23, wy2, wx3)
            ACC8(u30, wy3, wx0) ACC8(u31, wy3, wx1) ACC8(u32, wy3, wx2) ACC8(u33, wy3, wx3)
            #undef ACC8

            // channel c = slot*8 + j -> tile[j][slot][bin], row stride 51 (odd)
            tile[0*16*51 + slot*51 + bin] = a0;
            tile[1*16*51 + slot*51 + bin] = a1;
            tile[2*16*51 + slot*51 + bin] = a2;
            tile[3*16*51 + slot*51 + bin] = a3;
            tile[4*16*51 + slot*51 + bin] = a4;
            tile[5*16*51 + slot*51 + bin] = a5;
            tile[6*16*51 + slot*51 + bin] = a6;
            tile[7*16*51 + slot*51 + bin] = a7;
        }
    }
    __syncthreads();

    // One contiguous, fully-coalesced 25 KB write per block.
    // chunk -> output channel base: level*256 + half*128.
    float* dst = out + ((size_t)k*C3 + (size_t)chunk*128) * BINS;
    for (int i = tid; i < 128*BINS; i += 256) {
        const int c = i / BINS;              // local channel 0..127
        const int bin = i - c*BINS;
        dst[i] = tile[(c & 7)*16*51 + (c >> 3)*51 + bin];
    }
}

// ---------------------------------------------------------------------------
// Fallback (no workspace): direct gather from sources, one float per thread.
// ---------------------------------------------------------------------------
__device__ __forceinline__ float feat_val(const float* __restrict__ x0,
                                          const float* __restrict__ x1,
                                          const float* __restrict__ x2,
                                          int b, int y, int x, int c) {
    if (c < CC) {
        return x0[(((size_t)b*CC + c)*HH + y)*HH + x];
    }
    const float* src;
    int L; float s, t; int cl;
    if (c < 2*CC) { src = x1; L = 50; s = 0.5f;  t = 0.25f;  cl = c - CC; }
    else          { src = x2; L = 25; s = 0.25f; t = 0.375f; cl = c - 2*CC; }
    float cy = fminf(fmaxf((float)y * s - t, 0.0f), (float)(L - 1));
    float cx = fminf(fmaxf((float)x * s - t, 0.0f), (float)(L - 1));
    int yl = (int)cy, xl = (int)cx;
    int yh = min(yl + 1, L - 1), xh = min(xl + 1, L - 1);
    float fy = cy - (float)yl, fx = cx - (float)xl;
    const float* p = src + (((size_t)b*CC + cl)*L)*L;
    float v00 = p[yl*L + xl], v01 = p[yl*L + xh];
    float v10 = p[yh*L + xl], v11 = p[yh*L + xh];
    float hy = 1.0f - fy, hx = 1.0f - fx;
    return v00*(hy*hx) + v01*(hy*fx) + v10*(fy*hx) + v11*(fy*fx);
}

__global__ __launch_bounds__(256) void roi_fallback(const float* __restrict__ x0,
                                                    const float* __restrict__ x1,
                                                    const float* __restrict__ x2,
                                                    const float* __restrict__ boxes,
                                                    const float* __restrict__ ratio_hw,
                                                    const float* __restrict__ offset_tl,
                                                    float* __restrict__ out) {
    __shared__ int   s_ylo[NSAMP], s_yhi[NSAMP], s_xlo[NSAMP], s_xhi[NSAMP];
    __shared__ float s_fy[NSAMP], s_fx[NSAMP];
    __shared__ int   s_vy[NSAMP], s_vx[NSAMP];

    const int tid = threadIdx.x;
    const int k = blockIdx.x;
    const int chunk = blockIdx.y;
    const int b = k >> 8;

    if (tid < 2*NSAMP) {
        float r0 = ratio_hw[0], o0 = offset_tl[0];
        float scale = (float)HH / (1250.0f * r0 + 2.0f * o0);
        float rH  = ratio_hw[2*b],  rW   = ratio_hw[2*b + 1];
        float top = offset_tl[2*b], left = offset_tl[2*b + 1];
        const float* bx = boxes + (size_t)k * 4;
        bool isx = (tid >= NSAMP);
        int i = isx ? tid - NSAMP : tid;
        float a, e;
        if (isx) { a = (bx[0]*rW + left)*scale; e = (bx[2]*rW + left)*scale; }
        else     { a = (bx[1]*rH + top)*scale;  e = (bx[3]*rH + top)*scale;  }
        float len = fmaxf(e - a, 1.0f);
        float bs = len * (1.0f / (float)OUTB);
        float g = (float)(i >> 1) + 0.25f + 0.5f * (float)(i & 1);
        float p = a + g * bs;
        int v = (p >= -1.0f && p <= (float)HH) ? 1 : 0;
        float cc = fminf(fmaxf(p, 0.0f), (float)(HH - 1));
        int lo = (int)floorf(cc);
        int hi = min(lo + 1, HH - 1);
        float fr = cc - (float)lo;
        if (isx) { s_xlo[i] = lo; s_xhi[i] = hi; s_fx[i] = fr; s_vx[i] = v; }
        else     { s_ylo[i] = lo; s_yhi[i] = hi; s_fy[i] = fr; s_vy[i] = v; }
    }
    __syncthreads();

    const int c = chunk * 256 + tid;
    for (int oy = 0; oy < OUTB; ++oy) {
        for (int ox = 0; ox < OUTB; ++ox) {
            float acc = 0.0f;
            #pragma unroll
            for (int sy = 0; sy < SR; ++sy) {
                const int iy = oy*SR + sy;
                #pragma unroll
                for (int sx = 0; sx < SR; ++sx) {
                    const int ix = ox*SR + sx;
                    if (s_vy[iy] && s_vx[ix]) {
                        const float fy = s_fy[iy], fx = s_fx[ix];
                        const float hy = 1.0f - fy, hx = 1.0f - fx;
                        float v00 = feat_val(x0,x1,x2,b, s_ylo[iy], s_xlo[ix], c);
                        float v01 = feat_val(x0,x1,x2,b, s_ylo[iy], s_xhi[ix], c);
                        float v10 = feat_val(x0,x1,x2,b, s_yhi[iy], s_xlo[ix], c);
                        float v11 = feat_val(x0,x1,x2,b, s_yhi[iy], s_xhi[ix], c);
                        acc += v00*(hy*hx) + v01*(hy*fx) + v10*(fy*hx) + v11*(fy*fx);
                    }
                }
            }
            out[(size_t)k*C3*BINS + (size_t)c*BINS + oy*OUTB + ox] = acc * 0.25f;
        }
    }
}

extern "C" void kernel_launch(void* const* d_in, const int* in_sizes, int n_in,
                              void* d_out, int out_size, void* d_ws, size_t ws_size,
                              hipStream_t stream) {
    const float* x0       = (const float*)d_in[0];
    const float* x1       = (const float*)d_in[1];
    const float* x2       = (const float*)d_in[2];
    const float* boxes    = (const float*)d_in[3];
    const float* ratio_hw = (const float*)d_in[4];
    const float* off_tl   = (const float*)d_in[5];
    float* out = (float*)d_out;

    const size_t needW = (size_t)(NP0 + NP1 + NP2) * BB * CC * 2;  // 13.44 MB
    if (ws_size >= needW) {
        unsigned int* F0 = (unsigned int*)d_ws;
        unsigned int* F1 = F0 + (size_t)BB*NP0*CC/2;
        unsigned int* F2 = F1 + (size_t)BB*NP1*CC/2;
        transpose_all<<<dim3(207, 4, BB), 256, 0, stream>>>(x0, x1, x2, F0, F1, F2);
        roi8<<<dim3(KK, 6), 256, 0, stream>>>((const uint4*)F0, (const uint4*)F1,
                                              (const uint4*)F2,
                                              boxes, ratio_hw, off_tl, out);
    } else {
        roi_fallback<<<dim3(KK, 3), 256, 0, stream>>>(x0, x1, x2,
                                                      boxes, ratio_hw, off_tl, out);
    }
}